// Round 5
// baseline (339.153 us; speedup 1.0000x reference)
//
#include <hip/hip_runtime.h>

typedef _Float16 h8 __attribute__((ext_vector_type(8)));
typedef _Float16 h4 __attribute__((ext_vector_type(4)));
typedef float f4 __attribute__((ext_vector_type(4)));

typedef __attribute__((address_space(1))) const void GV;
typedef __attribute__((address_space(3))) void SV;

__device__ __forceinline__ void async16(const void* g, void* s) {
  __builtin_amdgcn_global_load_lds((GV*)g, (SV*)s, 16, 0, 0);
}

// sizes:
// x: (4,4096,1024) fp32   -> M=16384 rows, K=1024
// w_qkv: (3072,1024) fp32 -> rows e = h*192 + d*3 + t
// mem_kv: (2,16,4,64) fp32
// mask: (4,4096) int32
// out: (4,4096,1024) fp32
//
// ALL qkv intermediates stored TRANSPOSED, f16, full-sector h4 stores:
//   Pt  [(b*16+h)*64 + d] * 4096 + l_local   exp(q/8)
//   EKt [(b*16+h)*64 + d] * 4096 + l_local   mask ? exp(k) : 0
//   Vt  [(b*16+h)*64 + d] * 4096 + l_local   v
// NOTE: second index is LOCAL to batch b (0..4095) — bh carries the batch.

#define X4N 4194304   // 16777216/4

// ---------------- kernel 1: fp32 -> f16 convert (x then w) ----------------
__global__ __launch_bounds__(256) void cvt_f16(const float4* __restrict__ x,
                                               const float4* __restrict__ w,
                                               h4* __restrict__ xh,
                                               h4* __restrict__ wh) {
  int i = blockIdx.x * 256 + threadIdx.x;
  if (i < X4N) {
    float4 v = x[i];
    h4 o = {(_Float16)v.x, (_Float16)v.y, (_Float16)v.z, (_Float16)v.w};
    xh[i] = o;
  } else {
    int j = i - X4N;
    float4 v = w[j];
    h4 o = {(_Float16)v.x, (_Float16)v.y, (_Float16)v.z, (_Float16)v.w};
    wh[j] = o;
  }
}

// ---------------- kernel 2: qkv GEMM 128x128, fused exp + transpose ------
__global__ __launch_bounds__(256, 3) void gemm_qkv(const _Float16* __restrict__ A,
                                                   const _Float16* __restrict__ W,
                                                   const int* __restrict__ mask,
                                                   _Float16* __restrict__ Pt,
                                                   _Float16* __restrict__ EKt,
                                                   _Float16* __restrict__ Vt) {
  __shared__ _Float16 As[128 * 32];   // 8 KB
  __shared__ _Float16 Bs[128 * 32];   // 8 KB
  const int tid = threadIdx.x;
  const int lane = tid & 63, wid = tid >> 6;
  const int wm = wid & 1, wn = wid >> 1;
  const int l15 = lane & 15, quad = lane >> 4;
  const int m0 = blockIdx.y * 128;
  const int n0 = blockIdx.x * 128;

  const f4 z = {0.f, 0.f, 0.f, 0.f};
  f4 acc[4][4];
#pragma unroll
  for (int i = 0; i < 4; ++i)
#pragma unroll
    for (int j = 0; j < 4; ++j) acc[i][j] = z;

  for (int kt = 0; kt < 32; ++kt) {
    const int k0 = kt * 32;
#pragma unroll
    for (int it = 0; it < 2; ++it) {
      const int c = wid + it * 4;         // 8 chunks of 1KB per tile
      const int idx = c * 64 + lane;      // 0..511
      const int row = idx >> 2, cg = idx & 3;
      async16(A + ((size_t)(m0 + row) * 1024 + k0 + cg * 8), As + c * 512);
      async16(W + ((size_t)(n0 + row) * 1024 + k0 + cg * 8), Bs + c * 512);
    }
    __syncthreads();
    h8 af[4], bf[4];
#pragma unroll
    for (int i = 0; i < 4; ++i)
      af[i] = *(const h8*)&As[(wm * 64 + i * 16 + l15) * 32 + quad * 8];
#pragma unroll
    for (int j = 0; j < 4; ++j)
      bf[j] = *(const h8*)&Bs[(wn * 64 + j * 16 + l15) * 32 + quad * 8];
#pragma unroll
    for (int i = 0; i < 4; ++i)
#pragma unroll
      for (int j = 0; j < 4; ++j)
        acc[i][j] = __builtin_amdgcn_mfma_f32_16x16x32_f16(af[i], bf[j], acc[i][j], 0, 0, 0);
    __syncthreads();
  }

  // epilogue: col cl -> (h,d,t). All three tensors get transposed h4 stores
  // (4 consecutive n = the 4 acc regs) -> full 64-B sectors within the block.
  const int b = m0 >> 12;
  _Float16* const dsts[3] = {Pt, EKt, Vt};
#pragma unroll
  for (int i = 0; i < 4; ++i) {
    const int rl = (m0 & 4095) + wm * 64 + i * 16 + quad * 4;  // local n in b
    const int rg = m0 + wm * 64 + i * 16 + quad * 4;           // global row
#pragma unroll
    for (int j = 0; j < 4; ++j) {
      const int cl = n0 + wn * 64 + j * 16 + l15;
      const int h = cl / 192;
      const int d3 = cl - h * 192;
      const int d = d3 / 3;
      const int t = d3 - d * 3;
      const size_t tr = ((size_t)((b * 16 + h) * 64 + d)) * 4096 + rl;
      h4 o;
      if (t == 0) {
#pragma unroll
        for (int r = 0; r < 4; ++r) o[r] = (_Float16)__expf(acc[i][j][r] * 0.125f);
      } else if (t == 1) {
#pragma unroll
        for (int r = 0; r < 4; ++r)
          o[r] = (_Float16)(mask[rg + r] ? __expf(acc[i][j][r]) : 0.f);
      } else {
#pragma unroll
        for (int r = 0; r < 4; ++r) o[r] = (_Float16)acc[i][j][r];
      }
      *(h4*)&dsts[t][tr] = o;
    }
  }
}

// ---------------- kernel 3: ctx partials, register-direct MFMA -----------
// grid (16 chunks, 64 bh). No LDS, no barriers. Wave w owns d in [16w,16w+16).
// part layout per (bh,chunk): 4096 acc[d][e] + 64 den[d].
__global__ __launch_bounds__(256) void ctx_partial(const _Float16* __restrict__ EKt,
                                                   const _Float16* __restrict__ Vt,
                                                   float* __restrict__ part) {
  const int chunk = blockIdx.x;  // 0..15
  const int bh = blockIdx.y;     // 0..63
  const int tid = threadIdx.x;
  const int lane = tid & 63, wid = tid >> 6;
  const int l15 = lane & 15, quad = lane >> 4;

  const f4 z = {0.f, 0.f, 0.f, 0.f};
  f4 acc[5];
#pragma unroll
  for (int i = 0; i < 5; ++i) acc[i] = z;

  h8 bones;
  {
    const _Float16 o1 = (l15 == 0) ? (_Float16)1.f : (_Float16)0.f;
#pragma unroll
    for (int j = 0; j < 8; ++j) bones[j] = o1;
  }

  const int ncol = chunk * 256 + quad * 8;
  const _Float16* ap = EKt + ((size_t)(bh * 64) + wid * 16 + l15) * 4096 + ncol;
  const _Float16* bp = Vt + ((size_t)(bh * 64) + l15) * 4096 + ncol;

#pragma unroll 2
  for (int s = 0; s < 8; ++s) {
    const int off = s * 32;
    h8 a = *(const h8*)(ap + off);
    h8 b0 = *(const h8*)(bp + off);
    h8 b1 = *(const h8*)(bp + (size_t)16 * 4096 + off);
    h8 b2 = *(const h8*)(bp + (size_t)32 * 4096 + off);
    h8 b3 = *(const h8*)(bp + (size_t)48 * 4096 + off);
    acc[0] = __builtin_amdgcn_mfma_f32_16x16x32_f16(a, b0, acc[0], 0, 0, 0);
    acc[1] = __builtin_amdgcn_mfma_f32_16x16x32_f16(a, b1, acc[1], 0, 0, 0);
    acc[2] = __builtin_amdgcn_mfma_f32_16x16x32_f16(a, b2, acc[2], 0, 0, 0);
    acc[3] = __builtin_amdgcn_mfma_f32_16x16x32_f16(a, b3, acc[3], 0, 0, 0);
    acc[4] = __builtin_amdgcn_mfma_f32_16x16x32_f16(a, bones, acc[4], 0, 0, 0);
  }

  const size_t pb = ((size_t)bh * 16 + chunk) * 4160;
  const int dw = wid * 16 + quad * 4;
#pragma unroll
  for (int et = 0; et < 4; ++et)
#pragma unroll
    for (int r = 0; r < 4; ++r)
      part[pb + (size_t)(dw + r) * 64 + et * 16 + l15] = acc[et][r];
  if (l15 == 0) {
#pragma unroll
    for (int r = 0; r < 4; ++r) part[pb + 4096 + dw + r] = acc[4][r];
  }
}

// ---------------- kernel 4: reduce partials + memkv (fp32), store ctx^T --
// ctxt[bh*4096 + e*64 + d]  (e-major, d-contig -> B-frag contiguous for attn)
__global__ __launch_bounds__(256) void reduce_ctx(const float* __restrict__ part,
                                                  const float* __restrict__ memkv,
                                                  _Float16* __restrict__ ctxt) {
  const int bh = blockIdx.x;
  const int h = bh & 15;
  const int tid = threadIdx.x;
  __shared__ float inv[64];
  const size_t pb = (size_t)bh * 16 * 4160;
  if (tid < 64) {
    float s = 0.f;
#pragma unroll
    for (int c = 0; c < 16; ++c) s += part[pb + (size_t)c * 4160 + 4096 + tid];
#pragma unroll
    for (int j = 0; j < 4; ++j) s += __expf(memkv[(h * 4 + j) * 64 + tid]);
    inv[tid] = 1.0f / s;
  }
  __syncthreads();
  const int d = tid >> 2, e0 = (tid & 3) * 16;
  float emk[4];
#pragma unroll
  for (int j = 0; j < 4; ++j) emk[j] = __expf(memkv[(h * 4 + j) * 64 + d]);
  f4 s[4];
#pragma unroll
  for (int g = 0; g < 4; ++g) s[g] = f4{0.f, 0.f, 0.f, 0.f};
#pragma unroll
  for (int c = 0; c < 16; ++c)
#pragma unroll
    for (int g = 0; g < 4; ++g)
      s[g] += *(const f4*)&part[pb + (size_t)c * 4160 + (size_t)d * 64 + e0 + g * 4];
#pragma unroll
  for (int j = 0; j < 4; ++j) {
#pragma unroll
    for (int g = 0; g < 4; ++g) {
      f4 mv = *(const f4*)&memkv[4096 + (h * 4 + j) * 64 + e0 + g * 4];
      s[g] += emk[j] * mv;
    }
  }
  const float iv = inv[d];
#pragma unroll
  for (int g = 0; g < 4; ++g)
#pragma unroll
    for (int u = 0; u < 4; ++u)
      ctxt[(size_t)bh * 4096 + (size_t)(e0 + g * 4 + u) * 64 + d] =
          (_Float16)(s[g][u] * iv);
}

// ---------------- kernel 5: out = (P @ ctx)/s; Pt via LDS transpose ------
// grid (128 l-chunks, 16 heads). ctxt B-frags register-direct; Pt staged to
// LDS [d][l_local] and A-frags gathered via ds_read_u16.
__global__ __launch_bounds__(256) void attn_out(const _Float16* __restrict__ Pt,
                                                const _Float16* __restrict__ ctxt,
                                                const int* __restrict__ mask,
                                                float* __restrict__ out) {
  const int l0 = blockIdx.x * 128;       // global row base
  const int ll = l0 & 4095;              // batch-local row base (Pt indexing!)
  const int h = blockIdx.y;
  const int bh = (l0 >> 12) * 16 + h;
  const int tid = threadIdx.x;
  const int lane = tid & 63, wid = tid >> 6;
  const int l15 = lane & 15, quad = lane >> 4;

  __shared__ _Float16 pl[64 * 128];  // [d][l_local], 16 KB

#pragma unroll
  for (int it = 0; it < 4; ++it) {
    const int c = it * 256 + tid;          // 0..1023
    const int d = c >> 4, cc = c & 15;
    async16(Pt + ((size_t)(bh * 64 + d)) * 4096 + ll + cc * 8, pl + c * 8);
  }

  h8 bf[2][4], bones;
  {
    const _Float16 o1 = (l15 == 0) ? (_Float16)1.f : (_Float16)0.f;
#pragma unroll
    for (int j = 0; j < 8; ++j) bones[j] = o1;
  }
#pragma unroll
  for (int ks = 0; ks < 2; ++ks)
#pragma unroll
    for (int et = 0; et < 4; ++et)
      bf[ks][et] = *(const h8*)&ctxt[(size_t)bh * 4096 +
                                     (size_t)(et * 16 + l15) * 64 + ks * 32 + quad * 8];
  __syncthreads();

  h8 af[2][2];
#pragma unroll
  for (int i = 0; i < 2; ++i) {
    const int m = wid * 32 + i * 16 + l15;
#pragma unroll
    for (int ks = 0; ks < 2; ++ks)
#pragma unroll
      for (int j = 0; j < 8; ++j)
        af[i][ks][j] = pl[(ks * 32 + quad * 8 + j) * 128 + m];
  }

  const f4 z = {0.f, 0.f, 0.f, 0.f};
  f4 acc[2][5];
#pragma unroll
  for (int i = 0; i < 2; ++i)
#pragma unroll
    for (int j = 0; j < 5; ++j) acc[i][j] = z;
#pragma unroll
  for (int i = 0; i < 2; ++i)
#pragma unroll
    for (int ks = 0; ks < 2; ++ks) {
#pragma unroll
      for (int et = 0; et < 4; ++et)
        acc[i][et] = __builtin_amdgcn_mfma_f32_16x16x32_f16(af[i][ks], bf[ks][et], acc[i][et], 0, 0, 0);
      acc[i][4] = __builtin_amdgcn_mfma_f32_16x16x32_f16(af[i][ks], bones, acc[i][4], 0, 0, 0);
    }

#pragma unroll
  for (int i = 0; i < 2; ++i) {
#pragma unroll
    for (int r = 0; r < 4; ++r) {
      const int row = l0 + wid * 32 + i * 16 + quad * 4 + r;
      const float sb = __shfl(acc[i][4][r], lane & 48);  // den from col-0 lane
      const float iv = mask[row] ? 1.0f / sb : 0.0f;
#pragma unroll
      for (int et = 0; et < 4; ++et)
        out[(size_t)row * 1024 + h * 64 + et * 16 + l15] = acc[i][et][r] * iv;
    }
  }
}

// ---------------- launch ----------------
extern "C" void kernel_launch(void* const* d_in, const int* in_sizes, int n_in,
                              void* d_out, int out_size, void* d_ws, size_t ws_size,
                              hipStream_t stream) {
  const float* x = (const float*)d_in[0];      // 16777216
  const float* w = (const float*)d_in[1];      // 3145728
  const float* memkv = (const float*)d_in[2];  // 8192
  const int* mask = (const int*)d_in[3];       // 16384
  float* out = (float*)d_out;

  char* ws = (char*)d_ws;
  _Float16* xh   = (_Float16*)(ws + 0);           //  33,554,432
  _Float16* wh   = (_Float16*)(ws + 33554432);    //   6,291,456
  _Float16* Pt   = (_Float16*)(ws + 39845888);    //  33,554,432
  _Float16* EKt  = (_Float16*)(ws + 73400320);    //  33,554,432
  _Float16* Vt   = (_Float16*)(ws + 106954752);   //  33,554,432
  float*    part = (float*)(ws + 140509184);      //  17,039,360
  _Float16* ctxt = (_Float16*)(ws + 157548544);   //     524,288  (~150.8 MB)

  cvt_f16<<<dim3(19456), dim3(256), 0, stream>>>((const float4*)x, (const float4*)w,
                                                 (h4*)xh, (h4*)wh);
  gemm_qkv<<<dim3(24, 128), dim3(256), 0, stream>>>(xh, wh, mask, Pt, EKt, Vt);
  ctx_partial<<<dim3(16, 64), dim3(256), 0, stream>>>(EKt, Vt, part);
  reduce_ctx<<<dim3(64), dim3(256), 0, stream>>>(part, memkv, ctxt);
  attn_out<<<dim3(128, 16), dim3(256), 0, stream>>>(Pt, ctxt, mask, out);
}

// Round 6
// 291.214 us; speedup vs baseline: 1.1646x; 1.1646x over previous
//
#include <hip/hip_runtime.h>

typedef _Float16 h8 __attribute__((ext_vector_type(8)));
typedef _Float16 h4 __attribute__((ext_vector_type(4)));
typedef float f4 __attribute__((ext_vector_type(4)));

typedef __attribute__((address_space(1))) const void GV;
typedef __attribute__((address_space(3))) void SV;

__device__ __forceinline__ void async16(const void* g, void* s) {
  __builtin_amdgcn_global_load_lds((GV*)g, (SV*)s, 16, 0, 0);
}

// x: (4,4096,1024) fp32; w_qkv: (3072,1024) fp32 rows e=h*192+d*3+t;
// mem_kv: (2,16,4,64) fp32; mask: (4,4096) int32; out: (4,4096,1024) fp32.
//
// wh is PERMUTED during convert:
//   rows [0,2048):  [h][c]  c<64 -> k-row h*192+c*3+1 ; c>=64 -> v-row h*192+(c-64)*3+2
//   rows [2048,3072): [h][d] -> q-row h*192+d*3
// So gemm n-tile bx<16 = head bx's full (k|v) -> ctx fused in epilogue,
// EK/V never written to HBM. q-tiles store P n-major (no write amplification,
// and P is then directly the attn A-fragment layout).

#define X4N 4194304   // 16777216/4
#define W4N 786432    // 3145728/4

// ---------------- kernel 1: fp32 -> f16 convert; W rows permuted ----------
__global__ __launch_bounds__(256) void cvt_f16(const float4* __restrict__ x,
                                               const float4* __restrict__ w,
                                               h4* __restrict__ xh,
                                               h4* __restrict__ wh) {
  int i = blockIdx.x * 256 + threadIdx.x;
  if (i < X4N) {
    float4 v = x[i];
    h4 o = {(_Float16)v.x, (_Float16)v.y, (_Float16)v.z, (_Float16)v.w};
    xh[i] = o;
  } else {
    int j = i - X4N;                 // 0..786431
    int rp = j >> 8, kc = j & 255;   // dest row, k-chunk (4 floats)
    int sr;
    if (rp < 2048) {
      int h = rp >> 7, c = rp & 127;
      sr = h * 192 + ((c < 64) ? (c * 3 + 1) : ((c - 64) * 3 + 2));
    } else {
      int q = rp - 2048;
      sr = (q >> 6) * 192 + (q & 63) * 3;
    }
    float4 v = w[sr * 256 + kc];
    h4 o = {(_Float16)v.x, (_Float16)v.y, (_Float16)v.z, (_Float16)v.w};
    wh[rp * 256 + kc] = o;
  }
}

// ---------------- kernel 2: fused qkv GEMM + ctx-partial / P epilogue ----
// grid (24 n-tiles, 128 m-tiles). bx<16: kv-tile (head bx). bx>=16: q-tile.
// part layout per (bh, m-chunk): 4096 ctx[d][e] + 64 den[d] floats.
__global__ __launch_bounds__(256, 3) void gemm_fused(const _Float16* __restrict__ A,
                                                     const _Float16* __restrict__ W,
                                                     const int* __restrict__ mask,
                                                     _Float16* __restrict__ P,
                                                     float* __restrict__ part) {
  __shared__ _Float16 smem[128 * 128];  // 32 KB; first 16 KB = staging
  _Float16* const As = smem;
  _Float16* const Bs = smem + 4096;
  const int tid = threadIdx.x;
  const int lane = tid & 63, wid = tid >> 6;
  const int wm = wid & 1, wn = wid >> 1;
  const int l15 = lane & 15, quad = lane >> 4;
  const int m0 = blockIdx.y * 128;
  const int n0 = blockIdx.x * 128;

  const f4 z = {0.f, 0.f, 0.f, 0.f};
  f4 acc[4][4];
#pragma unroll
  for (int i = 0; i < 4; ++i)
#pragma unroll
    for (int j = 0; j < 4; ++j) acc[i][j] = z;

  for (int kt = 0; kt < 32; ++kt) {
    const int k0 = kt * 32;
#pragma unroll
    for (int it = 0; it < 2; ++it) {
      const int c = wid + it * 4;         // 8 chunks of 1KB per tile
      const int idx = c * 64 + lane;      // 0..511
      const int row = idx >> 2, cg = idx & 3;
      async16(A + ((size_t)(m0 + row) * 1024 + k0 + cg * 8), As + c * 512);
      async16(W + ((size_t)(n0 + row) * 1024 + k0 + cg * 8), Bs + c * 512);
    }
    __syncthreads();
    h8 af[4], bf[4];
#pragma unroll
    for (int i = 0; i < 4; ++i)
      af[i] = *(const h8*)&As[(wm * 64 + i * 16 + l15) * 32 + quad * 8];
#pragma unroll
    for (int j = 0; j < 4; ++j)
      bf[j] = *(const h8*)&Bs[(wn * 64 + j * 16 + l15) * 32 + quad * 8];
#pragma unroll
    for (int i = 0; i < 4; ++i)
#pragma unroll
      for (int j = 0; j < 4; ++j)
        acc[i][j] = __builtin_amdgcn_mfma_f32_16x16x32_f16(af[i], bf[j], acc[i][j], 0, 0, 0);
    __syncthreads();
  }

  if (n0 < 2048) {
    // ---- kv epilogue: exp(k)+mask, LDS round-trip, ctx partial via MFMA --
    const int h = n0 >> 7;
    const int b = m0 >> 12;
    const int lc = (m0 & 4095) >> 7;     // m-chunk within batch, 0..31
    const int bh = b * 16 + h;
    // write ek (cols 0..63) / v (cols 64..127) into XOR-swizzled LDS [c][128n]
#pragma unroll
    for (int i = 0; i < 4; ++i) {
      const int nb = wm * 64 + i * 16 + quad * 4;
#pragma unroll
      for (int j = 0; j < 4; ++j) {
        const int c = wn * 64 + j * 16 + l15;
        h4 o;
        if (wn == 0) {
#pragma unroll
          for (int r = 0; r < 4; ++r)
            o[r] = (_Float16)(mask[m0 + nb + r] ? __expf(acc[i][j][r]) : 0.f);
        } else {
#pragma unroll
          for (int r = 0; r < 4; ++r) o[r] = (_Float16)acc[i][j][r];
        }
        *(h4*)&smem[c * 128 + (nb ^ (l15 * 8))] = o;
      }
    }
    __syncthreads();
    // ctx[d][e] = sum_n ek[n][d] v[n][e]; wave w owns d-stripe [16w,16w+16)
    f4 cacc[5];
#pragma unroll
    for (int i = 0; i < 5; ++i) cacc[i] = z;
    h8 bones;
    {
      const _Float16 o1 = (l15 == 0) ? (_Float16)1.f : (_Float16)0.f;
#pragma unroll
      for (int j = 0; j < 8; ++j) bones[j] = o1;
    }
    const int ds = wid * 16;
#pragma unroll
    for (int ks = 0; ks < 4; ++ks) {
      const int nb2 = (ks * 32 + quad * 8) ^ (l15 * 8);
      h8 a = *(const h8*)&smem[(ds + l15) * 128 + nb2];
#pragma unroll
      for (int et = 0; et < 4; ++et) {
        h8 bv = *(const h8*)&smem[(64 + et * 16 + l15) * 128 + nb2];
        cacc[et] = __builtin_amdgcn_mfma_f32_16x16x32_f16(a, bv, cacc[et], 0, 0, 0);
      }
      cacc[4] = __builtin_amdgcn_mfma_f32_16x16x32_f16(a, bones, cacc[4], 0, 0, 0);
    }
    const size_t pb = ((size_t)bh * 32 + lc) * 4160;
    const int dw = ds + quad * 4;
#pragma unroll
    for (int et = 0; et < 4; ++et)
#pragma unroll
      for (int r = 0; r < 4; ++r)
        part[pb + (size_t)(dw + r) * 64 + et * 16 + l15] = cacc[et][r];
    if (l15 == 0) {
#pragma unroll
      for (int r = 0; r < 4; ++r) part[pb + 4096 + dw + r] = cacc[4][r];
    }
  } else {
    // ---- q epilogue: P = exp(q/8), n-major scalar stores (no write amp) --
#pragma unroll
    for (int i = 0; i < 4; ++i) {
      const int rg = m0 + wm * 64 + i * 16 + quad * 4;
#pragma unroll
      for (int j = 0; j < 4; ++j) {
        const int qc = (n0 - 2048) + wn * 64 + j * 16 + l15;  // = h*64+d
#pragma unroll
        for (int r = 0; r < 4; ++r)
          P[(size_t)(rg + r) * 1024 + qc] = (_Float16)__expf(acc[i][j][r] * 0.125f);
      }
    }
  }
}

// ---------------- kernel 3: reduce partials + memkv (fp32), store ctx^T --
// ctxt[bh*4096 + e*64 + d]  (e-major, d-contig -> B-frag contiguous for attn)
__global__ __launch_bounds__(256) void reduce_ctx(const float* __restrict__ part,
                                                  const float* __restrict__ memkv,
                                                  _Float16* __restrict__ ctxt) {
  const int bh = blockIdx.x;
  const int h = bh & 15;
  const int tid = threadIdx.x;
  __shared__ float inv[64];
  const size_t pb = (size_t)bh * 32 * 4160;
  if (tid < 64) {
    float s = 0.f;
#pragma unroll
    for (int c = 0; c < 32; ++c) s += part[pb + (size_t)c * 4160 + 4096 + tid];
#pragma unroll
    for (int j = 0; j < 4; ++j) s += __expf(memkv[(h * 4 + j) * 64 + tid]);
    inv[tid] = 1.0f / s;
  }
  __syncthreads();
  const int d = tid >> 2, e0 = (tid & 3) * 16;
  float emk[4];
#pragma unroll
  for (int j = 0; j < 4; ++j) emk[j] = __expf(memkv[(h * 4 + j) * 64 + d]);
  f4 s[4];
#pragma unroll
  for (int g = 0; g < 4; ++g) s[g] = f4{0.f, 0.f, 0.f, 0.f};
#pragma unroll
  for (int c = 0; c < 32; ++c)
#pragma unroll
    for (int g = 0; g < 4; ++g)
      s[g] += *(const f4*)&part[pb + (size_t)c * 4160 + (size_t)d * 64 + e0 + g * 4];
#pragma unroll
  for (int j = 0; j < 4; ++j) {
#pragma unroll
    for (int g = 0; g < 4; ++g) {
      f4 mv = *(const f4*)&memkv[4096 + (h * 4 + j) * 64 + e0 + g * 4];
      s[g] += emk[j] * mv;
    }
  }
  const float iv = inv[d];
#pragma unroll
  for (int g = 0; g < 4; ++g)
#pragma unroll
    for (int u = 0; u < 4; ++u)
      ctxt[(size_t)bh * 4096 + (size_t)(e0 + g * 4 + u) * 64 + d] =
          (_Float16)(s[g][u] * iv);
}

// ---------------- kernel 4: out = (P @ ctx)/s, register-direct MFMA ------
// grid (128 l-chunks, 16 heads). No LDS, no barriers. (r3-verified structure)
__global__ __launch_bounds__(256) void attn_out(const _Float16* __restrict__ P,
                                                const _Float16* __restrict__ ctxt,
                                                const int* __restrict__ mask,
                                                float* __restrict__ out) {
  const int l0 = blockIdx.x * 128;
  const int h = blockIdx.y;
  const int bh = (l0 >> 12) * 16 + h;
  const int tid = threadIdx.x;
  const int lane = tid & 63, wid = tid >> 6;
  const int l15 = lane & 15, quad = lane >> 4;

  h8 af[2][2], bf[2][4], bones;
  {
    const _Float16 o1 = (l15 == 0) ? (_Float16)1.f : (_Float16)0.f;
#pragma unroll
    for (int j = 0; j < 8; ++j) bones[j] = o1;
  }
#pragma unroll
  for (int i = 0; i < 2; ++i)
#pragma unroll
    for (int ks = 0; ks < 2; ++ks)
      af[i][ks] = *(const h8*)&P[(size_t)(l0 + wid * 32 + i * 16 + l15) * 1024 +
                                 h * 64 + ks * 32 + quad * 8];
#pragma unroll
  for (int ks = 0; ks < 2; ++ks)
#pragma unroll
    for (int et = 0; et < 4; ++et)
      bf[ks][et] = *(const h8*)&ctxt[(size_t)bh * 4096 +
                                     (size_t)(et * 16 + l15) * 64 + ks * 32 + quad * 8];

  const f4 z = {0.f, 0.f, 0.f, 0.f};
  f4 acc[2][5];
#pragma unroll
  for (int i = 0; i < 2; ++i)
#pragma unroll
    for (int j = 0; j < 5; ++j) acc[i][j] = z;
#pragma unroll
  for (int i = 0; i < 2; ++i)
#pragma unroll
    for (int ks = 0; ks < 2; ++ks) {
#pragma unroll
      for (int et = 0; et < 4; ++et)
        acc[i][et] = __builtin_amdgcn_mfma_f32_16x16x32_f16(af[i][ks], bf[ks][et], acc[i][et], 0, 0, 0);
      acc[i][4] = __builtin_amdgcn_mfma_f32_16x16x32_f16(af[i][ks], bones, acc[i][4], 0, 0, 0);
    }

#pragma unroll
  for (int i = 0; i < 2; ++i) {
#pragma unroll
    for (int r = 0; r < 4; ++r) {
      const int row = l0 + wid * 32 + i * 16 + quad * 4 + r;
      const float sb = __shfl(acc[i][4][r], lane & 48);  // den from col-0 lane
      const float iv = mask[row] ? 1.0f / sb : 0.0f;
#pragma unroll
      for (int et = 0; et < 4; ++et)
        out[(size_t)row * 1024 + h * 64 + et * 16 + l15] = acc[i][et][r] * iv;
    }
  }
}

// ---------------- launch ----------------
extern "C" void kernel_launch(void* const* d_in, const int* in_sizes, int n_in,
                              void* d_out, int out_size, void* d_ws, size_t ws_size,
                              hipStream_t stream) {
  const float* x = (const float*)d_in[0];      // 16777216
  const float* w = (const float*)d_in[1];      // 3145728
  const float* memkv = (const float*)d_in[2];  // 8192
  const int* mask = (const int*)d_in[3];       // 16384
  float* out = (float*)d_out;

  char* ws = (char*)d_ws;
  _Float16* xh   = (_Float16*)(ws + 0);           //  33,554,432
  _Float16* wh   = (_Float16*)(ws + 33554432);    //   6,291,456 (permuted)
  _Float16* P    = (_Float16*)(ws + 39845888);    //  33,554,432
  float*    part = (float*)(ws + 73400320);       //  34,078,720
  _Float16* ctxt = (_Float16*)(ws + 107479040);   //     524,288  (~103 MB)

  cvt_f16<<<dim3(19456), dim3(256), 0, stream>>>((const float4*)x, (const float4*)w,
                                                 (h4*)xh, (h4*)wh);
  gemm_fused<<<dim3(24, 128), dim3(256), 0, stream>>>(xh, wh, mask, P, part);
  reduce_ctx<<<dim3(64), dim3(256), 0, stream>>>(part, memkv, ctxt);
  attn_out<<<dim3(128, 16), dim3(256), 0, stream>>>(P, ctxt, mask, out);
}